// Round 1
// baseline (960.948 us; speedup 1.0000x reference)
//
#include <hip/hip_runtime.h>
#include <hip/hip_bf16.h>

#define LRELU(v) ((v) > 0.f ? (v) : 0.2f * (v))

// ---------------------------------------------------------------------------
// lrelu(X[M,K] @ W[K,64] + b) -> out[M,64].  One wave per row, lane = out col.
__global__ __launch_bounds__(256) void embed_kernel(
    const float* __restrict__ X, const float* __restrict__ W,
    const float* __restrict__ b, float* __restrict__ out, int M, int K) {
  int lane = threadIdx.x & 63;
  int r = blockIdx.x * 4 + (threadIdx.x >> 6);
  if (r >= M) return;
  float acc = b[lane];
  const float* Xr = X + (size_t)r * K;
  for (int k = 0; k < K; ++k) acc = fmaf(Xr[k], W[(size_t)k * 64 + lane], acc);
  acc = LRELU(acc);
  out[(size_t)r * 64 + lane] = acc;
}

// ---------------------------------------------------------------------------
// C[M,640] = A[M,64] @ W[64,640].  One wave per 8 rows; lane = col within head,
// 10 heads per lane, 80 accumulators.  M must be a multiple of 8 (10000/40000 are).
__global__ __launch_bounds__(256) void gemm_k64_kernel(
    const float* __restrict__ A, const float* __restrict__ W,
    float* __restrict__ C, int M) {
  const int lane = threadIdx.x & 63;
  const int r0 = (blockIdx.x * 4 + (threadIdx.x >> 6)) * 8;
  if (r0 >= M) return;
  float acc[8][10];
#pragma unroll
  for (int r = 0; r < 8; ++r)
#pragma unroll
    for (int h = 0; h < 10; ++h) acc[r][h] = 0.f;
  const float* Arow = A + (size_t)r0 * 64;
  for (int k = 0; k < 64; ++k) {
    float w[10];
#pragma unroll
    for (int h = 0; h < 10; ++h) w[h] = W[(size_t)k * 640 + h * 64 + lane];
    float a[8];
#pragma unroll
    for (int r = 0; r < 8; ++r) a[r] = Arow[r * 64 + k];
#pragma unroll
    for (int r = 0; r < 8; ++r)
#pragma unroll
      for (int h = 0; h < 10; ++h) acc[r][h] = fmaf(a[r], w[h], acc[r][h]);
  }
#pragma unroll
  for (int r = 0; r < 8; ++r) {
    float* Crow = C + (size_t)(r0 + r) * 640;
#pragma unroll
    for (int h = 0; h < 10; ++h) Crow[h * 64 + lane] = acc[r][h];
  }
}

// ---------------------------------------------------------------------------
// Per-edge attention + message + scatter.  One wave per edge, lane = feature.
// hi = lrelu(P[row]+Q[e]), hj = lrelu(P[col]+Q[e]);
// alpha[h] = softmax_h( lrelu(hi.att1 + hj.att2)*inv_std*gamma[h] + beta[h] );
// agg[row] += sum_h alpha[h]*hj[h]   (mean over heads folded into finalize)
__global__ __launch_bounds__(256) void edge_attn_kernel(
    const float* __restrict__ P, const float* __restrict__ Q,
    const int* __restrict__ row, const int* __restrict__ col,
    const float* __restrict__ att, const float* __restrict__ gamma,
    const float* __restrict__ beta, float* __restrict__ agg, int E_) {
  int lane = threadIdx.x & 63;
  int e = blockIdx.x * 4 + (threadIdx.x >> 6);
  if (e >= E_) return;
  int r = row[e], c = col[e];
  const float* Pr = P + (size_t)r * 640;
  const float* Pc = P + (size_t)c * 640;
  const float* Qe = Q + (size_t)e * 640;
  float hj[10], val[10];
#pragma unroll
  for (int h = 0; h < 10; ++h) {
    float q = Qe[h * 64 + lane];
    float hi = Pr[h * 64 + lane] + q;
    float hjv = Pc[h * 64 + lane] + q;
    hi = LRELU(hi);
    hjv = LRELU(hjv);
    hj[h] = hjv;
    val[h] = fmaf(hi, att[h * 128 + lane], hjv * att[h * 128 + 64 + lane]);
  }
#pragma unroll
  for (int h = 0; h < 10; ++h) {
    float v = val[h];
#pragma unroll
    for (int off = 32; off; off >>= 1) v += __shfl_xor(v, off);
    val[h] = v;
  }
  const float inv_std = 0.9999950000374997f;  // 1/sqrt(1+1e-5)
  float mx = -1e30f;
#pragma unroll
  for (int h = 0; h < 10; ++h) {
    float a = val[h];
    a = LRELU(a);
    a = fmaf(a * inv_std, gamma[h], beta[h]);
    val[h] = a;
    mx = fmaxf(mx, a);
  }
  float ssum = 0.f;
#pragma unroll
  for (int h = 0; h < 10; ++h) {
    float ex = expf(val[h] - mx);
    val[h] = ex;
    ssum += ex;
  }
  float inv = 1.0f / ssum;
  float m = 0.f;
#pragma unroll
  for (int h = 0; h < 10; ++h) m = fmaf(val[h] * inv, hj[h], m);
  atomicAdd(agg + (size_t)r * 64 + lane, m);
}

// ---------------------------------------------------------------------------
// h = [h +] agg/NH + b [+ h0]   mode 0: overwrite, 1: +h, 2: +h +h0
__global__ __launch_bounds__(256) void finalize_kernel(
    float* __restrict__ h, const float* __restrict__ agg,
    const float* __restrict__ b, const float* __restrict__ h0, int mode,
    int total) {
  int idx = blockIdx.x * 256 + threadIdx.x;
  if (idx >= total) return;
  int f = idx & 63;
  float v = fmaf(agg[idx], 0.1f, b[f]);
  if (mode >= 1) v += h[idx];
  if (mode == 2) v += h0[idx];
  h[idx] = v;
}

// ---------------------------------------------------------------------------
// score[n] = lrelu([h[n], gf[batch[n]]] @ W1 + b1) @ W2 + b2.  Wave per node.
__global__ __launch_bounds__(256) void score_kernel(
    const float* __restrict__ h, const int* __restrict__ batch,
    const float* __restrict__ gf, const float* __restrict__ W1,
    const float* __restrict__ b1, const float* __restrict__ W2,
    const float* __restrict__ b2, float* __restrict__ score, int N_) {
  int lane = threadIdx.x & 63;
  int n = blockIdx.x * 4 + (threadIdx.x >> 6);
  if (n >= N_) return;
  float acc = b1[lane];
  const float* hn = h + (size_t)n * 64;
#pragma unroll 8
  for (int k = 0; k < 64; ++k) acc = fmaf(hn[k], W1[k * 64 + lane], acc);
  const float* g = gf + (size_t)batch[n] * 108;
#pragma unroll 4
  for (int k = 0; k < 108; ++k) acc = fmaf(g[k], W1[(64 + k) * 64 + lane], acc);
  acc = LRELU(acc);
  float v = acc * W2[lane];
#pragma unroll
  for (int off = 32; off; off >>= 1) v += __shfl_xor(v, off);
  if (lane == 0) score[n] = v + b2[0];
}

// ---------------------------------------------------------------------------
// Graph boundary offsets from sorted batch_idx: start[g]..start[g+1]
__global__ void bounds_kernel(const int* __restrict__ batch,
                              int* __restrict__ start, int N_, int G_) {
  int n = blockIdx.x * blockDim.x + threadIdx.x;
  if (n >= N_) return;
  int b = batch[n];
  int bp = (n == 0) ? -1 : batch[n - 1];
  for (int g = bp + 1; g <= b; ++g) start[g] = n;
  if (n == N_ - 1)
    for (int g = b + 1; g <= G_; ++g) start[g] = N_;
}

// ---------------------------------------------------------------------------
// Per-graph softmax-attention pool + output MLP.  One block per graph.
__global__ __launch_bounds__(256) void pool_out_kernel(
    const float* __restrict__ h, const float* __restrict__ score,
    const int* __restrict__ start, const float* __restrict__ W1,
    const float* __restrict__ b1, const float* __restrict__ W2,
    const float* __restrict__ b2, float* __restrict__ out) {
  int g = blockIdx.x;
  int s0 = start[g], s1 = start[g + 1];
  int tid = threadIdx.x;
  __shared__ float red[256];
  __shared__ float pool[64];
  __shared__ float sh_smax, sh_denom;
  // pass 1: max score
  float lm = -1e30f;
  for (int n = s0 + tid; n < s1; n += 256) lm = fmaxf(lm, score[n]);
  red[tid] = lm;
  __syncthreads();
  for (int off = 128; off; off >>= 1) {
    if (tid < off) red[tid] = fmaxf(red[tid], red[tid + off]);
    __syncthreads();
  }
  if (tid == 0) sh_smax = red[0];
  __syncthreads();
  float smax = sh_smax;
  __syncthreads();
  // pass 2: denom
  float ls = 0.f;
  for (int n = s0 + tid; n < s1; n += 256) ls += expf(score[n] - smax);
  red[tid] = ls;
  __syncthreads();
  for (int off = 128; off; off >>= 1) {
    if (tid < off) red[tid] += red[tid + off];
    __syncthreads();
  }
  if (tid == 0) sh_denom = red[0];
  __syncthreads();
  float denom = sh_denom;
  float invd = denom > 0.f ? 1.0f / denom : 0.f;
  __syncthreads();
  // pass 3: weighted pool
  int f = tid & 63, sub = tid >> 6;
  float acc = 0.f;
  for (int n = s0 + sub; n < s1; n += 4)
    acc = fmaf(expf(score[n] - smax), h[(size_t)n * 64 + f], acc);
  red[tid] = acc;
  __syncthreads();
  if (tid < 64)
    pool[tid] = (red[tid] + red[tid + 64] + red[tid + 128] + red[tid + 192]) * invd;
  __syncthreads();
  // output head: relu(pool @ W1 + b1) @ W2 + b2
  if (tid < 64) {
    float a = b1[tid];
#pragma unroll 8
    for (int k = 0; k < 64; ++k) a = fmaf(pool[k], W1[k * 64 + tid], a);
    a = fmaxf(a, 0.f);
    red[tid] = a * W2[tid];
  }
  __syncthreads();
  if (tid == 0) {
    float s = 0.f;
    for (int k = 0; k < 64; ++k) s += red[k];
    out[g] = s + b2[0];
  }
}

// ---------------------------------------------------------------------------
extern "C" void kernel_launch(void* const* d_in, const int* in_sizes, int n_in,
                              void* d_out, int out_size, void* d_ws,
                              size_t ws_size, hipStream_t stream) {
  const float* x          = (const float*)d_in[0];
  const int*   edge_index = (const int*)d_in[1];
  const float* edge_attr  = (const float*)d_in[2];
  const int*   batch_idx  = (const int*)d_in[3];
  const float* gf         = (const float*)d_in[4];
  const float* node_W     = (const float*)d_in[5];
  const float* node_b     = (const float*)d_in[6];
  const float* edge_W     = (const float*)d_in[7];
  const float* edge_b     = (const float*)d_in[8];
  const float* conv_W     = (const float*)d_in[9];
  const float* conv_att   = (const float*)d_in[10];
  const float* conv_b     = (const float*)d_in[11];
  const float* conv_gamma = (const float*)d_in[12];
  const float* conv_beta  = (const float*)d_in[13];
  const float* ga_W1      = (const float*)d_in[14];
  const float* ga_b1      = (const float*)d_in[15];
  const float* ga_W2      = (const float*)d_in[16];
  const float* ga_b2      = (const float*)d_in[17];
  const float* out_W1     = (const float*)d_in[18];
  const float* out_b1     = (const float*)d_in[19];
  const float* out_W2     = (const float*)d_in[20];
  const float* out_b2     = (const float*)d_in[21];
  float* out = (float*)d_out;

  const int N = in_sizes[3];        // 10000
  const int E = in_sizes[2] / 50;   // 40000
  const int G = in_sizes[4] / 108;  // 128
  const int L = 5;

  float* ws = (float*)d_ws;
  float* h    = ws;  ws += (size_t)N * 64;
  float* h0   = ws;  ws += (size_t)N * 64;
  float* ea   = ws;  ws += (size_t)E * 64;
  float* P    = ws;  ws += (size_t)N * 640;
  float* Q    = ws;  ws += (size_t)E * 640;
  float* agg  = ws;  ws += (size_t)N * 64;
  float* scr  = ws;  ws += N;
  int* gstart = (int*)ws;

  const int* row = edge_index;
  const int* col = edge_index + E;

  embed_kernel<<<(N + 3) / 4, 256, 0, stream>>>(x, node_W, node_b, h0, N, 92);
  embed_kernel<<<(E + 3) / 4, 256, 0, stream>>>(edge_attr, edge_W, edge_b, ea, E, 50);

  for (int i = 0; i < L; ++i) {
    const float* Wi = conv_W + (size_t)i * 128 * 640;
    // P = h @ W_top   [N,640]
    gemm_k64_kernel<<<(N / 8 + 3) / 4, 256, 0, stream>>>(i == 0 ? h0 : h, Wi, P, N);
    // Q = ea @ W_bot  [E,640]
    gemm_k64_kernel<<<(E / 8 + 3) / 4, 256, 0, stream>>>(ea, Wi + 64 * 640, Q, E);
    hipMemsetAsync(agg, 0, (size_t)N * 64 * sizeof(float), stream);
    edge_attn_kernel<<<(E + 3) / 4, 256, 0, stream>>>(
        P, Q, row, col, conv_att + (size_t)i * 1280, conv_gamma + i * 10,
        conv_beta + i * 10, agg, E);
    int mode = (i == 0) ? 0 : (i == L - 1 ? 2 : 1);
    finalize_kernel<<<(N * 64 + 255) / 256, 256, 0, stream>>>(
        h, agg, conv_b + i * 64, h0, mode, N * 64);
  }

  score_kernel<<<(N + 3) / 4, 256, 0, stream>>>(h, batch_idx, gf, ga_W1, ga_b1,
                                                ga_W2, ga_b2, scr, N);
  bounds_kernel<<<(N + 255) / 256, 256, 0, stream>>>(batch_idx, gstart, N, G);
  pool_out_kernel<<<G, 256, 0, stream>>>(h, scr, gstart, out_W1, out_b1, out_W2,
                                         out_b2, out);
}

// Round 2
// 849.219 us; speedup vs baseline: 1.1316x; 1.1316x over previous
//
#include <hip/hip_runtime.h>
#include <hip/hip_bf16.h>

#define LRELU(v) ((v) > 0.f ? (v) : 0.2f * (v))

// ---------------------------------------------------------------------------
// lrelu(X[M,K] @ W[K,64] + b) -> out[M,64].  One wave per row, lane = out col.
__global__ __launch_bounds__(256) void embed_kernel(
    const float* __restrict__ X, const float* __restrict__ W,
    const float* __restrict__ b, float* __restrict__ out, int M, int K) {
  int lane = threadIdx.x & 63;
  int r = blockIdx.x * 4 + (threadIdx.x >> 6);
  if (r >= M) return;
  float acc = b[lane];
  const float* Xr = X + (size_t)r * K;
  for (int k = 0; k < K; ++k) acc = fmaf(Xr[k], W[(size_t)k * 64 + lane], acc);
  acc = LRELU(acc);
  out[(size_t)r * 64 + lane] = acc;
}

// ---------------------------------------------------------------------------
// C[M,640] = A[M,64] @ W[64,640].  ROWS rows per wave; lane = col within head,
// 10 heads per lane.
template <int ROWS>
__global__ __launch_bounds__(256) void gemm_k64_kernel(
    const float* __restrict__ A, const float* __restrict__ W,
    float* __restrict__ C, int M) {
  const int lane = threadIdx.x & 63;
  const int r0 = (blockIdx.x * 4 + (threadIdx.x >> 6)) * ROWS;
  if (r0 >= M) return;
  float acc[ROWS][10];
#pragma unroll
  for (int r = 0; r < ROWS; ++r)
#pragma unroll
    for (int h = 0; h < 10; ++h) acc[r][h] = 0.f;
  const float* Arow = A + (size_t)r0 * 64;
  for (int k = 0; k < 64; ++k) {
    float w[10];
#pragma unroll
    for (int h = 0; h < 10; ++h) w[h] = W[(size_t)k * 640 + h * 64 + lane];
    float a[ROWS];
#pragma unroll
    for (int r = 0; r < ROWS; ++r) a[r] = Arow[r * 64 + k];
#pragma unroll
    for (int r = 0; r < ROWS; ++r)
#pragma unroll
      for (int h = 0; h < 10; ++h) acc[r][h] = fmaf(a[r], w[h], acc[r][h]);
  }
#pragma unroll
  for (int r = 0; r < ROWS; ++r) {
    float* Crow = C + (size_t)(r0 + r) * 640;
#pragma unroll
    for (int h = 0; h < 10; ++h) Crow[h * 64 + lane] = acc[r][h];
  }
}

// ---------------------------------------------------------------------------
// Fused: Q = ea@W_bot computed in-register (8 edges/wave), then per-edge
// attention + message + scatter.  Lane = feature.
__global__ __launch_bounds__(256) void edge_fused_kernel(
    const float* __restrict__ P, const float* __restrict__ ea,
    const float* __restrict__ Wbot,  // [64, 640]
    const int* __restrict__ row, const int* __restrict__ col,
    const float* __restrict__ att, const float* __restrict__ gamma,
    const float* __restrict__ beta, float* __restrict__ agg, int E_) {
  const int lane = threadIdx.x & 63;
  const int wv = blockIdx.x * 4 + (threadIdx.x >> 6);
  const int e0 = wv * 8;
  if (e0 >= E_) return;

  // Preload ea rows (coalesced) for 8 edges.
  float eareg[8];
#pragma unroll
  for (int r = 0; r < 8; ++r) {
    int e = e0 + r < E_ ? e0 + r : E_ - 1;
    eareg[r] = ea[(size_t)e * 64 + lane];
  }

  // Q accumulation: qacc[r][h] = sum_k ea[e_r][k] * Wbot[k][h*64+lane]
  float qacc[8][10];
#pragma unroll
  for (int r = 0; r < 8; ++r)
#pragma unroll
    for (int h = 0; h < 10; ++h) qacc[r][h] = 0.f;
  for (int k = 0; k < 64; ++k) {
    float w[10];
#pragma unroll
    for (int h = 0; h < 10; ++h) w[h] = Wbot[k * 640 + h * 64 + lane];
    float a[8];
#pragma unroll
    for (int r = 0; r < 8; ++r) a[r] = __shfl(eareg[r], k);
#pragma unroll
    for (int r = 0; r < 8; ++r)
#pragma unroll
      for (int h = 0; h < 10; ++h) qacc[r][h] = fmaf(a[r], w[h], qacc[r][h]);
  }

  const float inv_std = 0.9999950000374997f;  // 1/sqrt(1+1e-5)
#pragma unroll
  for (int r = 0; r < 8; ++r) {
    int e = e0 + r;
    if (e >= E_) break;
    int ri = row[e], ci = col[e];
    const float* Pr = P + (size_t)ri * 640;
    const float* Pc = P + (size_t)ci * 640;
    float hj[10], val[10];
#pragma unroll
    for (int h = 0; h < 10; ++h) {
      float q = qacc[r][h];
      float hi = Pr[h * 64 + lane] + q;
      float hjv = Pc[h * 64 + lane] + q;
      hi = LRELU(hi);
      hjv = LRELU(hjv);
      hj[h] = hjv;
      val[h] = fmaf(hi, att[h * 128 + lane], hjv * att[h * 128 + 64 + lane]);
    }
#pragma unroll
    for (int h = 0; h < 10; ++h) {
      float v = val[h];
#pragma unroll
      for (int off = 32; off; off >>= 1) v += __shfl_xor(v, off);
      val[h] = v;
    }
    float mx = -1e30f;
#pragma unroll
    for (int h = 0; h < 10; ++h) {
      float a = val[h];
      a = LRELU(a);
      a = fmaf(a * inv_std, gamma[h], beta[h]);
      val[h] = a;
      mx = fmaxf(mx, a);
    }
    float ssum = 0.f;
#pragma unroll
    for (int h = 0; h < 10; ++h) {
      float ex = __expf(val[h] - mx);
      val[h] = ex;
      ssum += ex;
    }
    float inv = 1.0f / ssum;
    float m = 0.f;
#pragma unroll
    for (int h = 0; h < 10; ++h) m = fmaf(val[h] * inv, hj[h], m);
    atomicAdd(agg + (size_t)ri * 64 + lane, m);
  }
}

// ---------------------------------------------------------------------------
// h = [h +] agg/NH + b [+ h0]   mode 0: overwrite, 1: +h, 2: +h +h0
__global__ __launch_bounds__(256) void finalize_kernel(
    float* __restrict__ h, const float* __restrict__ agg,
    const float* __restrict__ b, const float* __restrict__ h0, int mode,
    int total) {
  int idx = blockIdx.x * 256 + threadIdx.x;
  if (idx >= total) return;
  int f = idx & 63;
  float v = fmaf(agg[idx], 0.1f, b[f]);
  if (mode >= 1) v += h[idx];
  if (mode == 2) v += h0[idx];
  h[idx] = v;
}

// ---------------------------------------------------------------------------
// score[n] = lrelu([h[n], gf[batch[n]]] @ W1 + b1) @ W2 + b2.  Wave per node.
__global__ __launch_bounds__(256) void score_kernel(
    const float* __restrict__ h, const int* __restrict__ batch,
    const float* __restrict__ gf, const float* __restrict__ W1,
    const float* __restrict__ b1, const float* __restrict__ W2,
    const float* __restrict__ b2, float* __restrict__ score, int N_) {
  int lane = threadIdx.x & 63;
  int n = blockIdx.x * 4 + (threadIdx.x >> 6);
  if (n >= N_) return;
  float acc = b1[lane];
  const float* hn = h + (size_t)n * 64;
#pragma unroll 8
  for (int k = 0; k < 64; ++k) acc = fmaf(hn[k], W1[k * 64 + lane], acc);
  const float* g = gf + (size_t)batch[n] * 108;
#pragma unroll 4
  for (int k = 0; k < 108; ++k) acc = fmaf(g[k], W1[(64 + k) * 64 + lane], acc);
  acc = LRELU(acc);
  float v = acc * W2[lane];
#pragma unroll
  for (int off = 32; off; off >>= 1) v += __shfl_xor(v, off);
  if (lane == 0) score[n] = v + b2[0];
}

// ---------------------------------------------------------------------------
// Graph boundary offsets from sorted batch_idx: start[g]..start[g+1]
__global__ void bounds_kernel(const int* __restrict__ batch,
                              int* __restrict__ start, int N_, int G_) {
  int n = blockIdx.x * blockDim.x + threadIdx.x;
  if (n >= N_) return;
  int b = batch[n];
  int bp = (n == 0) ? -1 : batch[n - 1];
  for (int g = bp + 1; g <= b; ++g) start[g] = n;
  if (n == N_ - 1)
    for (int g = b + 1; g <= G_; ++g) start[g] = N_;
}

// ---------------------------------------------------------------------------
// Per-graph softmax-attention pool + output MLP.  One block per graph.
__global__ __launch_bounds__(256) void pool_out_kernel(
    const float* __restrict__ h, const float* __restrict__ score,
    const int* __restrict__ start, const float* __restrict__ W1,
    const float* __restrict__ b1, const float* __restrict__ W2,
    const float* __restrict__ b2, float* __restrict__ out) {
  int g = blockIdx.x;
  int s0 = start[g], s1 = start[g + 1];
  int tid = threadIdx.x;
  __shared__ float red[256];
  __shared__ float pool[64];
  __shared__ float sh_smax, sh_denom;
  float lm = -1e30f;
  for (int n = s0 + tid; n < s1; n += 256) lm = fmaxf(lm, score[n]);
  red[tid] = lm;
  __syncthreads();
  for (int off = 128; off; off >>= 1) {
    if (tid < off) red[tid] = fmaxf(red[tid], red[tid + off]);
    __syncthreads();
  }
  if (tid == 0) sh_smax = red[0];
  __syncthreads();
  float smax = sh_smax;
  __syncthreads();
  float ls = 0.f;
  for (int n = s0 + tid; n < s1; n += 256) ls += __expf(score[n] - smax);
  red[tid] = ls;
  __syncthreads();
  for (int off = 128; off; off >>= 1) {
    if (tid < off) red[tid] += red[tid + off];
    __syncthreads();
  }
  if (tid == 0) sh_denom = red[0];
  __syncthreads();
  float denom = sh_denom;
  float invd = denom > 0.f ? 1.0f / denom : 0.f;
  __syncthreads();
  int f = tid & 63, sub = tid >> 6;
  float acc = 0.f;
  for (int n = s0 + sub; n < s1; n += 4)
    acc = fmaf(__expf(score[n] - smax), h[(size_t)n * 64 + f], acc);
  red[tid] = acc;
  __syncthreads();
  if (tid < 64)
    pool[tid] = (red[tid] + red[tid + 64] + red[tid + 128] + red[tid + 192]) * invd;
  __syncthreads();
  if (tid < 64) {
    float a = b1[tid];
#pragma unroll 8
    for (int k = 0; k < 64; ++k) a = fmaf(pool[k], W1[k * 64 + tid], a);
    a = fmaxf(a, 0.f);
    red[tid] = a * W2[tid];
  }
  __syncthreads();
  if (tid == 0) {
    float s = 0.f;
    for (int k = 0; k < 64; ++k) s += red[k];
    out[g] = s + b2[0];
  }
}

// ---------------------------------------------------------------------------
extern "C" void kernel_launch(void* const* d_in, const int* in_sizes, int n_in,
                              void* d_out, int out_size, void* d_ws,
                              size_t ws_size, hipStream_t stream) {
  const float* x          = (const float*)d_in[0];
  const int*   edge_index = (const int*)d_in[1];
  const float* edge_attr  = (const float*)d_in[2];
  const int*   batch_idx  = (const int*)d_in[3];
  const float* gf         = (const float*)d_in[4];
  const float* node_W     = (const float*)d_in[5];
  const float* node_b     = (const float*)d_in[6];
  const float* edge_W     = (const float*)d_in[7];
  const float* edge_b     = (const float*)d_in[8];
  const float* conv_W     = (const float*)d_in[9];
  const float* conv_att   = (const float*)d_in[10];
  const float* conv_b     = (const float*)d_in[11];
  const float* conv_gamma = (const float*)d_in[12];
  const float* conv_beta  = (const float*)d_in[13];
  const float* ga_W1      = (const float*)d_in[14];
  const float* ga_b1      = (const float*)d_in[15];
  const float* ga_W2      = (const float*)d_in[16];
  const float* ga_b2      = (const float*)d_in[17];
  const float* out_W1     = (const float*)d_in[18];
  const float* out_b1     = (const float*)d_in[19];
  const float* out_W2     = (const float*)d_in[20];
  const float* out_b2     = (const float*)d_in[21];
  float* out = (float*)d_out;

  const int N = in_sizes[3];        // 10000
  const int E = in_sizes[2] / 50;   // 40000
  const int G = in_sizes[4] / 108;  // 128
  const int L = 5;

  float* ws = (float*)d_ws;
  float* h    = ws;  ws += (size_t)N * 64;
  float* h0   = ws;  ws += (size_t)N * 64;
  float* ea   = ws;  ws += (size_t)E * 64;
  float* P    = ws;  ws += (size_t)N * 640;
  float* agg  = ws;  ws += (size_t)N * 64;
  float* scr  = ws;  ws += N;
  int* gstart = (int*)ws;

  const int* row = edge_index;
  const int* col = edge_index + E;

  embed_kernel<<<(N + 3) / 4, 256, 0, stream>>>(x, node_W, node_b, h0, N, 92);
  embed_kernel<<<(E + 3) / 4, 256, 0, stream>>>(edge_attr, edge_W, edge_b, ea, E, 50);

  for (int i = 0; i < L; ++i) {
    const float* Wi = conv_W + (size_t)i * 128 * 640;
    // P = h @ W_top   [N,640]
    gemm_k64_kernel<4><<<(N / 4 + 3) / 4, 256, 0, stream>>>(i == 0 ? h0 : h, Wi, P, N);
    hipMemsetAsync(agg, 0, (size_t)N * 64 * sizeof(float), stream);
    // Fused Q-gemm + attention + scatter
    int waves = (E + 7) / 8;
    edge_fused_kernel<<<(waves + 3) / 4, 256, 0, stream>>>(
        P, ea, Wi + 64 * 640, row, col, conv_att + (size_t)i * 1280,
        conv_gamma + i * 10, conv_beta + i * 10, agg, E);
    int mode = (i == 0) ? 0 : (i == L - 1 ? 2 : 1);
    finalize_kernel<<<(N * 64 + 255) / 256, 256, 0, stream>>>(
        h, agg, conv_b + i * 64, h0, mode, N * 64);
  }

  score_kernel<<<(N + 3) / 4, 256, 0, stream>>>(h, batch_idx, gf, ga_W1, ga_b1,
                                                ga_W2, ga_b2, scr, N);
  bounds_kernel<<<(N + 255) / 256, 256, 0, stream>>>(batch_idx, gstart, N, G);
  pool_out_kernel<<<G, 256, 0, stream>>>(h, scr, gstart, out_W1, out_b1, out_W2,
                                         out_b2, out);
}